// Round 1
// baseline (804.200 us; speedup 1.0000x reference)
//
#include <hip/hip_runtime.h>

typedef unsigned int u32;
typedef unsigned short u16;
typedef __bf16 bf16x8 __attribute__((ext_vector_type(8)));
typedef float f32x4 __attribute__((ext_vector_type(4)));

__device__ __forceinline__ u16 f2bf(float f) {
  u32 u = __builtin_bit_cast(u32, f);
  u32 r = (u + 0x7fffu + ((u >> 16) & 1u)) >> 16;   // RTNE
  return (u16)r;
}

// ---------------- CSR build ----------------
__global__ void zero_k(u32* __restrict__ p, int n) {
  int i = blockIdx.x * blockDim.x + threadIdx.x;
  if (i < n) p[i] = 0u;
}

__global__ void count_k(const int* __restrict__ dst, int E, u32* __restrict__ count) {
  int i = blockIdx.x * blockDim.x + threadIdx.x;
  if (i < E) atomicAdd(&count[dst[i]], 1u);
}

// single-block exclusive scan over N counts -> offsets[0..N]
__global__ void scan_k(const u32* __restrict__ count, int N, u32* __restrict__ offsets) {
  __shared__ u32 s[1024];
  int tid = threadIdx.x;
  int chunk = (N + 1023) / 1024;
  int lo = tid * chunk;
  int hi = lo + chunk; if (hi > N) hi = N;
  u32 sum = 0;
  for (int i = lo; i < hi && i >= 0; i++) if (i < N) sum += count[i];
  s[tid] = sum;
  __syncthreads();
  // Hillis-Steele inclusive scan (double-barrier form)
  for (int off = 1; off < 1024; off <<= 1) {
    u32 t = (tid >= off) ? s[tid - off] : 0u;
    __syncthreads();
    s[tid] += t;
    __syncthreads();
  }
  u32 run = s[tid] - sum;   // exclusive base for this chunk
  for (int i = lo; i < hi; i++) {
    if (i < N) { offsets[i] = run; run += count[i]; }
  }
  if (hi == N) offsets[N] = run;   // all such threads write the same total
}

__global__ void scatter_k(const int* __restrict__ src, const int* __restrict__ dst, int E,
                          const u32* __restrict__ offsets, u32* __restrict__ cursor,
                          int* __restrict__ ssrc) {
  int i = blockIdx.x * blockDim.x + threadIdx.x;
  if (i < E) {
    int d = dst[i];
    u32 pos = offsets[d] + atomicAdd(&cursor[d], 1u);
    ssrc[pos] = src[i];
  }
}

// ---------------- bf16 conversions ----------------
// x (N x 128 f32) -> comb[:, 0:128] bf16 (comb row stride 256)
__global__ void convx_k(const float* __restrict__ x, u16* __restrict__ comb, int n4) {
  int i = blockIdx.x * blockDim.x + threadIdx.x;
  if (i >= n4) return;
  size_t base = (size_t)i * 4;
  size_t row = base >> 7;
  int col = (int)(base & 127);
  const float4 v = *(const float4*)(x + base);
  ushort4 o = { f2bf(v.x), f2bf(v.y), f2bf(v.z), f2bf(v.w) };
  *(ushort4*)(comb + (row << 8) + col) = o;
}

__global__ void convw_k(const float* __restrict__ W, u16* __restrict__ wbf, int n4) {
  int i = blockIdx.x * blockDim.x + threadIdx.x;
  if (i >= n4) return;
  const float4 v = *(const float4*)(W + (size_t)i * 4);
  ushort4 o = { f2bf(v.x), f2bf(v.y), f2bf(v.z), f2bf(v.w) };
  *(ushort4*)(wbf + (size_t)i * 4) = o;
}

// ---------------- aggregate: one wave per node ----------------
__global__ __launch_bounds__(256) void agg_k(const int* __restrict__ ssrc,
                                             const u32* __restrict__ offsets,
                                             u16* comb, int N) {
  int wid = (blockIdx.x * blockDim.x + threadIdx.x) >> 6;
  int lane = threadIdx.x & 63;
  if (wid >= N) return;
  u32 s0 = offsets[wid], s1 = offsets[wid + 1];
  float ax = 0.f, ay = 0.f;
  for (u32 j = s0; j < s1; j++) {
    int s = ssrc[j];
    u32 v = *(const u32*)(comb + ((size_t)s << 8) + (lane << 1));
    ax += __builtin_bit_cast(float, v << 16);
    ay += __builtin_bit_cast(float, v & 0xffff0000u);
  }
  u32 deg = s1 - s0;
  float inv = 1.0f / (float)(deg > 0u ? deg : 1u);
  u32 o = (u32)f2bf(ax * inv) | ((u32)f2bf(ay * inv) << 16);
  *(u32*)(comb + ((size_t)wid << 8) + 128 + (lane << 1)) = o;
}

// ---------------- GEMM: comb (N x 256 bf16) @ Wbf^T (+bias) -> out (N x 128 f32) ----------------
// one wave per 16-row strip; A-slab in registers, B-fragments straight from L1/L2
__global__ __launch_bounds__(256) void gemm_k(const u16* __restrict__ comb,
                                              const u16* __restrict__ wbf,
                                              const float* __restrict__ bias,
                                              float* __restrict__ out, int nstrips) {
  int wave = threadIdx.x >> 6, lane = threadIdx.x & 63;
  int strip = blockIdx.x * 4 + wave;
  if (strip >= nstrips) return;
  int la = lane & 15, lb = lane >> 4;

  const u16* abase = comb + ((size_t)(strip * 16 + la) << 8) + lb * 8;
  bf16x8 a[8];
#pragma unroll
  for (int kb = 0; kb < 8; kb++) a[kb] = *(const bf16x8*)(abase + kb * 32);

#pragma unroll
  for (int ct = 0; ct < 8; ct++) {
    f32x4 acc = { 0.f, 0.f, 0.f, 0.f };
    const u16* bbase = wbf + ((size_t)(ct * 16 + la) << 8) + lb * 8;
#pragma unroll
    for (int kb = 0; kb < 8; kb++) {
      bf16x8 b = *(const bf16x8*)(bbase + kb * 32);
      acc = __builtin_amdgcn_mfma_f32_16x16x32_bf16(a[kb], b, acc, 0, 0, 0);
    }
    float bc = bias[ct * 16 + la];
    int r0 = strip * 16 + lb * 4;
#pragma unroll
    for (int j = 0; j < 4; j++)
      out[((size_t)(r0 + j) << 7) + ct * 16 + la] = acc[j] + bc;
  }
}

extern "C" void kernel_launch(void* const* d_in, const int* in_sizes, int n_in,
                              void* d_out, int out_size, void* d_ws, size_t ws_size,
                              hipStream_t stream) {
  const float* x    = (const float*)d_in[0];
  const int*   ei   = (const int*)d_in[1];
  const float* W    = (const float*)d_in[2];
  const float* bias = (const float*)d_in[3];
  const int N = in_sizes[0] / 128;
  const int E = in_sizes[1] / 2;
  const int* src = ei;
  const int* dst = ei + E;
  float* out = (float*)d_out;

  char* ws = (char*)d_ws;
  u32* count   = (u32*)ws;            // N
  u32* cursor  = count + N;           // N
  u32* offsets = cursor + N;          // N+1
  size_t off = (size_t)(3 * N + 1) * 4;
  int* ssrc = (int*)(ws + off);       // E
  off += (size_t)E * 4;
  off = (off + 255) & ~(size_t)255;
  u16* comb = (u16*)(ws + off);       // N*256 bf16 (x | mean)
  u16* wbf  = comb + (size_t)N * 256; // 128*256 bf16

  zero_k<<<(2 * N + 255) / 256, 256, 0, stream>>>(count, 2 * N);
  count_k<<<(E + 255) / 256, 256, 0, stream>>>(dst, E, count);
  scan_k<<<1, 1024, 0, stream>>>(count, N, offsets);
  scatter_k<<<(E + 255) / 256, 256, 0, stream>>>(src, dst, E, offsets, cursor, ssrc);
  convx_k<<<(N * 32 + 255) / 256, 256, 0, stream>>>(x, comb, N * 32);
  convw_k<<<(8192 + 255) / 256, 256, 0, stream>>>(W, wbf, 8192);
  agg_k<<<(N + 3) / 4, 256, 0, stream>>>(ssrc, offsets, comb, N);
  gemm_k<<<(N / 16 + 3) / 4, 256, 0, stream>>>(comb, wbf, bias, out, N / 16);
}

// Round 2
// 499.495 us; speedup vs baseline: 1.6100x; 1.6100x over previous
//
#include <hip/hip_runtime.h>

typedef unsigned int u32;
typedef unsigned short u16;
typedef __bf16 bf16x8 __attribute__((ext_vector_type(8)));
typedef float f32x4 __attribute__((ext_vector_type(4)));

__device__ __forceinline__ u16 f2bf(float f) {
  u32 u = __builtin_bit_cast(u32, f);
  u32 r = (u + 0x7fffu + ((u >> 16) & 1u)) >> 16;   // RTNE
  return (u16)r;
}
__device__ __forceinline__ float bfhi(u32 w) { return __builtin_bit_cast(float, w & 0xffff0000u); }
__device__ __forceinline__ float bflo(u32 w) { return __builtin_bit_cast(float, w << 16); }

// ---------------- CSR build ----------------
__global__ void zero_k(u32* __restrict__ p, int n) {
  int i = blockIdx.x * blockDim.x + threadIdx.x;
  if (i < n) p[i] = 0u;
}

__global__ void count_k(const int* __restrict__ dst, int E, u32* __restrict__ count) {
  int i = blockIdx.x * blockDim.x + threadIdx.x;
  if (i < E) atomicAdd(&count[dst[i]], 1u);
}

// phase 1: per-block (1024-wide) exclusive scan; local results into offsets, block sums into partials
__global__ __launch_bounds__(1024) void scan1_k(const u32* __restrict__ count, int N,
                                                u32* __restrict__ offsets, u32* __restrict__ partials) {
  __shared__ u32 s[1024];
  int tid = threadIdx.x;
  int i = blockIdx.x * 1024 + tid;
  u32 v = (i < N) ? count[i] : 0u;
  s[tid] = v;
  __syncthreads();
  for (int off = 1; off < 1024; off <<= 1) {
    u32 t = (tid >= off) ? s[tid - off] : 0u;
    __syncthreads();
    s[tid] += t;
    __syncthreads();
  }
  if (i < N) offsets[i] = s[tid] - v;            // exclusive, local to block
  if (tid == 1023) partials[blockIdx.x] = s[1023];
}

// phase 2: one block scans the partials (NB <= 128)
__global__ __launch_bounds__(128) void scan2_k(u32* __restrict__ partials, int NB) {
  __shared__ u32 s[128];
  int tid = threadIdx.x;
  u32 v = (tid < NB) ? partials[tid] : 0u;
  s[tid] = v;
  __syncthreads();
  for (int off = 1; off < 128; off <<= 1) {
    u32 t = (tid >= off) ? s[tid - off] : 0u;
    __syncthreads();
    s[tid] += t;
    __syncthreads();
  }
  if (tid < NB) partials[tid] = s[tid] - v;      // exclusive
  if (tid == 127) partials[NB] = s[127];         // total = E
}

// phase 3: add block bases; write offsets[N]
__global__ void scan3_k(u32* __restrict__ offsets, const u32* __restrict__ partials, int N, int NB) {
  int i = blockIdx.x * blockDim.x + threadIdx.x;
  if (i < N) offsets[i] += partials[i >> 10];
  else if (i == N) offsets[N] = partials[NB];
}

__global__ void scatter_k(const int* __restrict__ src, const int* __restrict__ dst, int E,
                          const u32* __restrict__ offsets, u32* __restrict__ cursor,
                          int* __restrict__ ssrc) {
  int i = blockIdx.x * blockDim.x + threadIdx.x;
  if (i < E) {
    int d = dst[i];
    u32 pos = offsets[d] + atomicAdd(&cursor[d], 1u);
    ssrc[pos] = src[i];
  }
}

// ---------------- bf16 conversions ----------------
__global__ void convx_k(const float* __restrict__ x, u16* __restrict__ comb, int n4) {
  int i = blockIdx.x * blockDim.x + threadIdx.x;
  if (i >= n4) return;
  size_t base = (size_t)i * 4;
  size_t row = base >> 7;
  int col = (int)(base & 127);
  const float4 v = *(const float4*)(x + base);
  ushort4 o = { f2bf(v.x), f2bf(v.y), f2bf(v.z), f2bf(v.w) };
  *(ushort4*)(comb + (row << 8) + col) = o;
}

__global__ void convw_k(const float* __restrict__ W, u16* __restrict__ wbf, int n4) {
  int i = blockIdx.x * blockDim.x + threadIdx.x;
  if (i >= n4) return;
  const float4 v = *(const float4*)(W + (size_t)i * 4);
  ushort4 o = { f2bf(v.x), f2bf(v.y), f2bf(v.z), f2bf(v.w) };
  *(ushort4*)(wbf + (size_t)i * 4) = o;
}

// ---------------- aggregate: one wave per node, 4 edges in flight ----------------
// lane = 16*sub + cl : sub in [0,4) picks the edge, cl in [0,16) picks 8 columns (16B)
__global__ __launch_bounds__(256) void agg_k(const int* __restrict__ ssrc,
                                             const u32* __restrict__ offsets,
                                             u16* comb, int N) {
  int wid = (blockIdx.x * blockDim.x + threadIdx.x) >> 6;
  int lane = threadIdx.x & 63;
  if (wid >= N) return;
  int sub = lane >> 4;
  int cl = lane & 15;
  u32 s0 = offsets[wid], s1 = offsets[wid + 1];
  float a0=0.f,a1=0.f,a2=0.f,a3=0.f,a4=0.f,a5=0.f,a6=0.f,a7=0.f;
  for (u32 j = s0 + sub; j < s1; j += 4) {
    int s = ssrc[j];
    uint4 v = *(const uint4*)(comb + ((size_t)s << 8) + (cl << 3));
    a0 += bflo(v.x); a1 += bfhi(v.x);
    a2 += bflo(v.y); a3 += bfhi(v.y);
    a4 += bflo(v.z); a5 += bfhi(v.z);
    a6 += bflo(v.w); a7 += bfhi(v.w);
  }
  // reduce the 4 sub-groups (lanes differing in bits 4 and 5)
  a0 += __shfl_xor(a0, 16); a1 += __shfl_xor(a1, 16);
  a2 += __shfl_xor(a2, 16); a3 += __shfl_xor(a3, 16);
  a4 += __shfl_xor(a4, 16); a5 += __shfl_xor(a5, 16);
  a6 += __shfl_xor(a6, 16); a7 += __shfl_xor(a7, 16);
  a0 += __shfl_xor(a0, 32); a1 += __shfl_xor(a1, 32);
  a2 += __shfl_xor(a2, 32); a3 += __shfl_xor(a3, 32);
  a4 += __shfl_xor(a4, 32); a5 += __shfl_xor(a5, 32);
  a6 += __shfl_xor(a6, 32); a7 += __shfl_xor(a7, 32);
  if (sub == 0) {
    u32 deg = s1 - s0;
    float inv = 1.0f / (float)(deg > 0u ? deg : 1u);
    uint4 o;
    o.x = (u32)f2bf(a0 * inv) | ((u32)f2bf(a1 * inv) << 16);
    o.y = (u32)f2bf(a2 * inv) | ((u32)f2bf(a3 * inv) << 16);
    o.z = (u32)f2bf(a4 * inv) | ((u32)f2bf(a5 * inv) << 16);
    o.w = (u32)f2bf(a6 * inv) | ((u32)f2bf(a7 * inv) << 16);
    *(uint4*)(comb + ((size_t)wid << 8) + 128 + (cl << 3)) = o;
  }
}

// ---------------- GEMM: comb (N x 256 bf16) @ Wbf^T (+bias) -> out (N x 128 f32) ----------------
__global__ __launch_bounds__(256) void gemm_k(const u16* __restrict__ comb,
                                              const u16* __restrict__ wbf,
                                              const float* __restrict__ bias,
                                              float* __restrict__ out, int nstrips) {
  int wave = threadIdx.x >> 6, lane = threadIdx.x & 63;
  int strip = blockIdx.x * 4 + wave;
  if (strip >= nstrips) return;
  int la = lane & 15, lb = lane >> 4;

  const u16* abase = comb + ((size_t)(strip * 16 + la) << 8) + lb * 8;
  bf16x8 a[8];
#pragma unroll
  for (int kb = 0; kb < 8; kb++) a[kb] = *(const bf16x8*)(abase + kb * 32);

#pragma unroll
  for (int ct = 0; ct < 8; ct++) {
    f32x4 acc = { 0.f, 0.f, 0.f, 0.f };
    const u16* bbase = wbf + ((size_t)(ct * 16 + la) << 8) + lb * 8;
#pragma unroll
    for (int kb = 0; kb < 8; kb++) {
      bf16x8 b = *(const bf16x8*)(bbase + kb * 32);
      acc = __builtin_amdgcn_mfma_f32_16x16x32_bf16(a[kb], b, acc, 0, 0, 0);
    }
    float bc = bias[ct * 16 + la];
    int r0 = strip * 16 + lb * 4;
#pragma unroll
    for (int j = 0; j < 4; j++)
      out[((size_t)(r0 + j) << 7) + ct * 16 + la] = acc[j] + bc;
  }
}

extern "C" void kernel_launch(void* const* d_in, const int* in_sizes, int n_in,
                              void* d_out, int out_size, void* d_ws, size_t ws_size,
                              hipStream_t stream) {
  const float* x    = (const float*)d_in[0];
  const int*   ei   = (const int*)d_in[1];
  const float* W    = (const float*)d_in[2];
  const float* bias = (const float*)d_in[3];
  const int N = in_sizes[0] / 128;
  const int E = in_sizes[1] / 2;
  const int NB = (N + 1023) / 1024;
  const int* src = ei;
  const int* dst = ei + E;
  float* out = (float*)d_out;

  char* ws = (char*)d_ws;
  u32* count   = (u32*)ws;              // N
  u32* cursor  = count + N;             // N
  u32* offsets = cursor + N;            // N+1
  u32* partials = offsets + N + 1;      // NB+1
  size_t off = (size_t)(3 * N + 2 + NB + 1) * 4;
  off = (off + 255) & ~(size_t)255;
  int* ssrc = (int*)(ws + off);         // E
  off += (size_t)E * 4;
  off = (off + 255) & ~(size_t)255;
  u16* comb = (u16*)(ws + off);         // N*256 bf16 (x | mean)
  u16* wbf  = comb + (size_t)N * 256;   // 128*256 bf16

  zero_k<<<(2 * N + 255) / 256, 256, 0, stream>>>(count, 2 * N);
  count_k<<<(E + 255) / 256, 256, 0, stream>>>(dst, E, count);
  scan1_k<<<NB, 1024, 0, stream>>>(count, N, offsets, partials);
  scan2_k<<<1, 128, 0, stream>>>(partials, NB);
  scan3_k<<<(N + 256) / 256, 256, 0, stream>>>(offsets, partials, N, NB);
  scatter_k<<<(E + 255) / 256, 256, 0, stream>>>(src, dst, E, offsets, cursor, ssrc);
  convx_k<<<(N * 32 + 255) / 256, 256, 0, stream>>>(x, comb, N * 32);
  convw_k<<<(8192 + 255) / 256, 256, 0, stream>>>(W, wbf, 8192);
  agg_k<<<(N + 3) / 4, 256, 0, stream>>>(ssrc, offsets, comb, N);
  gemm_k<<<(N / 16 + 3) / 4, 256, 0, stream>>>(comb, wbf, bias, out, N / 16);
}

// Round 3
// 355.433 us; speedup vs baseline: 2.2626x; 1.4053x over previous
//
#include <hip/hip_runtime.h>

typedef unsigned int u32;
typedef unsigned short u16;
typedef __bf16 bf16x8 __attribute__((ext_vector_type(8)));
typedef float f32x4 __attribute__((ext_vector_type(4)));

__device__ __forceinline__ u16 f2bf(float f) {
  u32 u = __builtin_bit_cast(u32, f);
  u32 r = (u + 0x7fffu + ((u >> 16) & 1u)) >> 16;   // RTNE
  return (u16)r;
}
__device__ __forceinline__ float bfhi(u32 w) { return __builtin_bit_cast(float, w & 0xffff0000u); }
__device__ __forceinline__ float bflo(u32 w) { return __builtin_bit_cast(float, w << 16); }

// ---------------- fused pre-pass: convx | zero count | convw ----------------
__global__ __launch_bounds__(256) void pre_k(const float* __restrict__ x, u16* __restrict__ comb,
                                             const float* __restrict__ W, u16* __restrict__ wbf,
                                             u32* __restrict__ count, int N, int nbx, int nbz) {
  int b = blockIdx.x, tid = threadIdx.x;
  if (b < nbx) {                       // x (N x 128 f32) -> comb[:,0:128] bf16 (row stride 256)
    int i = b * 256 + tid;
    if (i < N * 32) {
      size_t base = (size_t)i * 4;
      size_t row = base >> 7;
      int col = (int)(base & 127);
      const float4 v = *(const float4*)(x + base);
      ushort4 o = { f2bf(v.x), f2bf(v.y), f2bf(v.z), f2bf(v.w) };
      *(ushort4*)(comb + (row << 8) + col) = o;
    }
  } else if (b < nbx + nbz) {          // zero the count array
    int i = (b - nbx) * 256 + tid;
    if (i < N) count[i] = 0u;
  } else {                             // W (128 x 256 f32) -> bf16
    int i = (b - nbx - nbz) * 256 + tid;
    if (i < 8192) {
      const float4 v = *(const float4*)(W + (size_t)i * 4);
      ushort4 o = { f2bf(v.x), f2bf(v.y), f2bf(v.z), f2bf(v.w) };
      *(ushort4*)(wbf + (size_t)i * 4) = o;
    }
  }
}

// ---------------- count + local rank ----------------
__global__ void count_k(const int* __restrict__ dst, int E, u32* __restrict__ count,
                        u32* __restrict__ lpos) {
  int i = blockIdx.x * blockDim.x + threadIdx.x;
  if (i < E) lpos[i] = atomicAdd(&count[dst[i]], 1u);
}

// phase 1: per-block (1024-wide) exclusive scan (padded region included)
__global__ __launch_bounds__(1024) void scan1_k(const u32* __restrict__ count, int N,
                                                u32* __restrict__ offsets, u32* __restrict__ partials) {
  __shared__ u32 s[1024];
  int tid = threadIdx.x;
  int i = blockIdx.x * 1024 + tid;
  u32 v = (i < N) ? count[i] : 0u;
  s[tid] = v;
  __syncthreads();
  for (int off = 1; off < 1024; off <<= 1) {
    u32 t = (tid >= off) ? s[tid - off] : 0u;
    __syncthreads();
    s[tid] += t;
    __syncthreads();
  }
  offsets[i] = s[tid] - v;             // block-local exclusive (padding gets block total)
  if (tid == 1023) partials[blockIdx.x] = s[1023];
}

// phase 2: one block scans the partials (NB <= 128) -> exclusive block bases
__global__ __launch_bounds__(128) void scan2_k(u32* __restrict__ partials, int NB) {
  __shared__ u32 s[128];
  int tid = threadIdx.x;
  u32 v = (tid < NB) ? partials[tid] : 0u;
  s[tid] = v;
  __syncthreads();
  for (int off = 1; off < 128; off <<= 1) {
    u32 t = (tid >= off) ? s[tid - off] : 0u;
    __syncthreads();
    s[tid] += t;
    __syncthreads();
  }
  if (tid < NB) partials[tid] = s[tid] - v;
  if (tid == 127) partials[NB] = s[127];
}

// ---------------- scatter (no atomics) ----------------
__global__ void scatter_k(const int* __restrict__ src, const int* __restrict__ dst, int E,
                          const u32* __restrict__ offsets, const u32* __restrict__ partials,
                          const u32* __restrict__ lpos, int* __restrict__ ssrc) {
  int i = blockIdx.x * blockDim.x + threadIdx.x;
  if (i < E) {
    int d = dst[i];
    u32 pos = offsets[d] + partials[d >> 10] + lpos[i];
    ssrc[pos] = src[i];
  }
}

// ---------------- aggregate: one wave per node, 8 edges in flight ----------------
__global__ __launch_bounds__(256) void agg_k(const int* __restrict__ ssrc,
                                             const u32* __restrict__ offsets,
                                             const u32* __restrict__ partials,
                                             u16* comb, int N) {
  int wid = (blockIdx.x * blockDim.x + threadIdx.x) >> 6;
  int lane = threadIdx.x & 63;
  if (wid >= N) return;
  int sub = lane >> 4;
  int cl = lane & 15;
  u32 s0 = offsets[wid] + partials[wid >> 10];
  u32 s1 = offsets[wid + 1] + partials[(wid + 1) >> 10];
  float a0=0.f,a1=0.f,a2=0.f,a3=0.f,a4=0.f,a5=0.f,a6=0.f,a7=0.f;
  u32 j = s0 + sub;
  for (; j + 4 < s1; j += 8) {
    int sA = ssrc[j];
    int sB = ssrc[j + 4];
    uint4 vA = *(const uint4*)(comb + ((size_t)sA << 8) + (cl << 3));
    uint4 vB = *(const uint4*)(comb + ((size_t)sB << 8) + (cl << 3));
    a0 += bflo(vA.x); a1 += bfhi(vA.x);
    a2 += bflo(vA.y); a3 += bfhi(vA.y);
    a4 += bflo(vA.z); a5 += bfhi(vA.z);
    a6 += bflo(vA.w); a7 += bfhi(vA.w);
    a0 += bflo(vB.x); a1 += bfhi(vB.x);
    a2 += bflo(vB.y); a3 += bfhi(vB.y);
    a4 += bflo(vB.z); a5 += bfhi(vB.z);
    a6 += bflo(vB.w); a7 += bfhi(vB.w);
  }
  if (j < s1) {
    int s = ssrc[j];
    uint4 v = *(const uint4*)(comb + ((size_t)s << 8) + (cl << 3));
    a0 += bflo(v.x); a1 += bfhi(v.x);
    a2 += bflo(v.y); a3 += bfhi(v.y);
    a4 += bflo(v.z); a5 += bfhi(v.z);
    a6 += bflo(v.w); a7 += bfhi(v.w);
  }
  a0 += __shfl_xor(a0, 16); a1 += __shfl_xor(a1, 16);
  a2 += __shfl_xor(a2, 16); a3 += __shfl_xor(a3, 16);
  a4 += __shfl_xor(a4, 16); a5 += __shfl_xor(a5, 16);
  a6 += __shfl_xor(a6, 16); a7 += __shfl_xor(a7, 16);
  a0 += __shfl_xor(a0, 32); a1 += __shfl_xor(a1, 32);
  a2 += __shfl_xor(a2, 32); a3 += __shfl_xor(a3, 32);
  a4 += __shfl_xor(a4, 32); a5 += __shfl_xor(a5, 32);
  a6 += __shfl_xor(a6, 32); a7 += __shfl_xor(a7, 32);
  if (sub == 0) {
    u32 deg = s1 - s0;
    float inv = 1.0f / (float)(deg > 0u ? deg : 1u);
    uint4 o;
    o.x = (u32)f2bf(a0 * inv) | ((u32)f2bf(a1 * inv) << 16);
    o.y = (u32)f2bf(a2 * inv) | ((u32)f2bf(a3 * inv) << 16);
    o.z = (u32)f2bf(a4 * inv) | ((u32)f2bf(a5 * inv) << 16);
    o.w = (u32)f2bf(a6 * inv) | ((u32)f2bf(a7 * inv) << 16);
    *(uint4*)(comb + ((size_t)wid << 8) + 128 + (cl << 3)) = o;
  }
}

// ---------------- GEMM: comb (N x 256 bf16) @ Wbf^T (+bias) -> out (N x 128 f32) ----------------
__global__ __launch_bounds__(256) void gemm_k(const u16* __restrict__ comb,
                                              const u16* __restrict__ wbf,
                                              const float* __restrict__ bias,
                                              float* __restrict__ out, int nstrips) {
  int wave = threadIdx.x >> 6, lane = threadIdx.x & 63;
  int strip = blockIdx.x * 4 + wave;
  if (strip >= nstrips) return;
  int la = lane & 15, lb = lane >> 4;

  const u16* abase = comb + ((size_t)(strip * 16 + la) << 8) + lb * 8;
  bf16x8 a[8];
#pragma unroll
  for (int kb = 0; kb < 8; kb++) a[kb] = *(const bf16x8*)(abase + kb * 32);

#pragma unroll
  for (int ct = 0; ct < 8; ct++) {
    f32x4 acc = { 0.f, 0.f, 0.f, 0.f };
    const u16* bbase = wbf + ((size_t)(ct * 16 + la) << 8) + lb * 8;
#pragma unroll
    for (int kb = 0; kb < 8; kb++) {
      bf16x8 b = *(const bf16x8*)(bbase + kb * 32);
      acc = __builtin_amdgcn_mfma_f32_16x16x32_bf16(a[kb], b, acc, 0, 0, 0);
    }
    float bc = bias[ct * 16 + la];
    int r0 = strip * 16 + lb * 4;
#pragma unroll
    for (int j = 0; j < 4; j++)
      out[((size_t)(r0 + j) << 7) + ct * 16 + la] = acc[j] + bc;
  }
}

extern "C" void kernel_launch(void* const* d_in, const int* in_sizes, int n_in,
                              void* d_out, int out_size, void* d_ws, size_t ws_size,
                              hipStream_t stream) {
  const float* x    = (const float*)d_in[0];
  const int*   ei   = (const int*)d_in[1];
  const float* W    = (const float*)d_in[2];
  const float* bias = (const float*)d_in[3];
  const int N = in_sizes[0] / 128;
  const int E = in_sizes[1] / 2;
  const int NB = (N + 1023) / 1024;
  const int* src = ei;
  const int* dst = ei + E;
  float* out = (float*)d_out;

  // lpos lives in d_out (used as scratch before gemm overwrites it); E ints <= N*128 floats
  u32* lpos = (u32*)d_out;

  char* ws = (char*)d_ws;
  u32* count    = (u32*)ws;                 // N
  u32* offsets  = count + N;                // NB*1024 (padded)
  u32* partials = offsets + NB * 1024;      // NB+1
  size_t off = ((size_t)(N + NB * 1024 + NB + 1) * 4 + 255) & ~(size_t)255;
  int* ssrc = (int*)(ws + off);             // E
  off += (size_t)E * 4;
  off = (off + 255) & ~(size_t)255;
  u16* comb = (u16*)(ws + off);             // N*256 bf16 (x | mean)
  u16* wbf  = comb + (size_t)N * 256;       // 128*256 bf16

  const int nbx = (N * 32 + 255) / 256;
  const int nbz = (N + 255) / 256;
  pre_k<<<nbx + nbz + 32, 256, 0, stream>>>(x, comb, W, wbf, count, N, nbx, nbz);
  count_k<<<(E + 255) / 256, 256, 0, stream>>>(dst, E, count, lpos);
  scan1_k<<<NB, 1024, 0, stream>>>(count, N, offsets, partials);
  scan2_k<<<1, 128, 0, stream>>>(partials, NB);
  scatter_k<<<(E + 255) / 256, 256, 0, stream>>>(src, dst, E, offsets, partials, lpos, ssrc);
  agg_k<<<(N + 3) / 4, 256, 0, stream>>>(ssrc, offsets, partials, comb, N);
  gemm_k<<<(N / 16 + 3) / 4, 256, 0, stream>>>(comb, wbf, bias, out, N / 16);
}